// Round 18
// baseline (217.096 us; speedup 1.0000x reference)
//
#include <hip/hip_runtime.h>
#include <hip/hip_bf16.h>
#include <stdint.h>

#define B_ 4
#define T_ 2048
#define C_ 1024
#define H_ 16
#define DH_ 64
#define M_ (B_*T_)      // 8192
#define NQKV_ (3*C_)    // 3072
#define K_ C_           // 1024

typedef __attribute__((ext_vector_type(8))) short short8;
typedef __attribute__((ext_vector_type(4))) float f32x4;
typedef __attribute__((ext_vector_type(4))) unsigned short us4;

union BFC { __hip_bfloat16 h; unsigned short u; };
__device__ inline unsigned short f2b(float f){ BFC c; c.h = __float2bfloat16(f); return c.u; }

__device__ inline void gload_lds16(const void* g, void* l){
  __builtin_amdgcn_global_load_lds(
    (const __attribute__((address_space(1))) void*)(uintptr_t)g,
    (__attribute__((address_space(3))) void*)(uintptr_t)l,
    16, 0, 0);
}

// ---------------- fused fp32 -> bf16 convert (x, qkv_w, proj_w) ----------------
__global__ void cvt_all(const float* __restrict__ x,
                        const float* __restrict__ qw,
                        const float* __restrict__ pw,
                        __hip_bfloat16* __restrict__ xb,
                        __hip_bfloat16* __restrict__ qwb,
                        __hip_bfloat16* __restrict__ pwb)
{
  const int NX = M_ * K_ / 4;          // 2,097,152 float4
  const int NQ = NQKV_ * K_ / 4;       //   786,432
  const int NP = C_ * K_ / 4;          //   262,144
  int i = blockIdx.x * blockDim.x + threadIdx.x;
  int stride = gridDim.x * blockDim.x;
  for (; i < NX + NQ + NP; i += stride) {
    const float4* s;
    us4* d;
    int j = i;
    if (j < NX)            { s = (const float4*)x  + j; d = (us4*)xb  + j; }
    else if (j < NX + NQ)  { j -= NX; s = (const float4*)qw + j; d = (us4*)qwb + j; }
    else                   { j -= NX + NQ; s = (const float4*)pw + j; d = (us4*)pwb + j; }
    float4 v = *s;
    us4 o;
    o.x = f2b(v.x); o.y = f2b(v.y); o.z = f2b(v.z); o.w = f2b(v.w);
    *d = o;
  }
}

// ---------------- GEMM: Y[M,N] = A[M,K] * B[N,K]^T + bias ----------------
// Tile 256 x (64*NW), 1024 thr = 16 waves (4x4), per-wave 64 x (16*NW).
// BK=64, rows 128 B, proven swizzle ((r&7)<<4) both sides (0 conflicts).
// bx-MAJOR decode (R15: by-major streams all of A through each XCD L2, 134MB
// fetch; bx-major = 57.6MB). 2-phase issue-early prefetch + one syncthreads
// per K-step. R17's counted-vmcnt ring was NEUTRAL on qkv (drain wasn't the
// limiter) and regressed proj -> this 2-phase version is the keeper.
// Structure plateau note: 16 waves = 1 block/CU (regs cap residency); LDS
// read-issue (~224 ds_read_b128/step/CU) is the standing limit (~91.5us qkv).
// NW=3 (qkv): grid 512 = 2 balanced rounds. NW=2 (proj): grid 256 = 1 round.
template<int NW>
__global__ __launch_bounds__(1024) void gemm_bt(
    const __hip_bfloat16* __restrict__ A,
    const __hip_bfloat16* __restrict__ Bw,
    const float* __restrict__ bias,
    int mode, int nbx,
    __hip_bfloat16* __restrict__ qdst,
    __hip_bfloat16* __restrict__ kdst,
    __hip_bfloat16* __restrict__ vdst,
    float* __restrict__ fdst)
{
  __shared__ char a_lds[2][32768];        // 256 rows x 128 B, swz ((r&7)<<4)
  __shared__ char b_lds[2][NW * 8192];    // 64*NW rows x 128 B

  const int tid = threadIdx.x;            // 0..1023
  const int lane = tid & 63;
  const int w = tid >> 6;                 // 0..15
  const int l15 = lane & 15;
  const int lhi = lane >> 4;
  const int wm = w >> 2, wn = w & 3;      // wave grid 4 x 4

  const int nwg = gridDim.x;
  const int q8 = nwg >> 3;
  const int lb = (blockIdx.x & 7) * q8 + (blockIdx.x >> 3);
  const int bx = lb % nbx, by = lb / nbx;   // bx-major (A panels L2-resident)
  const int row0 = by * 256;
  const int col0 = bx * (64 * NW);

  // staging decode: linear dest byte L -> row r = L>>7, src col = (L&127)^swz
  int arow[2], acol[2];
#pragma unroll
  for (int i = 0; i < 2; ++i) {
    int L = i * 16384 + tid * 16;
    int r = L >> 7;
    int cb = (L & 127) ^ ((r & 7) << 4);
    arow[i] = r; acol[i] = cb >> 1;
  }
  int brow0, bcol0, brow1 = 0, bcol1 = 0;
  {
    int L = tid * 16;
    int r = L >> 7;
    int cb = (L & 127) ^ ((r & 7) << 4);
    brow0 = r; bcol0 = cb >> 1;
  }
  const bool b1act = (NW == 4) || (NW == 3 && tid < 512);
  if (b1act) {
    int L = 16384 + tid * 16;
    int r = L >> 7;
    int cb = (L & 127) ^ ((r & 7) << 4);
    brow1 = r; bcol1 = cb >> 1;
  }

  const f32x4 zf = {0.f, 0.f, 0.f, 0.f};
  f32x4 acc[4][NW];
#pragma unroll
  for (int m = 0; m < 4; ++m)
#pragma unroll
    for (int n = 0; n < NW; ++n) acc[m][n] = zf;

  const short* Ag = (const short*)A;
  const short* Bg = (const short*)Bw;

#define STAGE(kt, buf)                                                         \
  do {                                                                         \
    gload_lds16(Ag + (size_t)(row0 + arow[0]) * K_ + (kt) * 64 + acol[0],      \
                &a_lds[buf][tid * 16]);                                        \
    gload_lds16(Ag + (size_t)(row0 + arow[1]) * K_ + (kt) * 64 + acol[1],      \
                &a_lds[buf][16384 + tid * 16]);                                \
    gload_lds16(Bg + (size_t)(col0 + brow0) * K_ + (kt) * 64 + bcol0,          \
                &b_lds[buf][tid * 16]);                                        \
    if (b1act)                                                                 \
      gload_lds16(Bg + (size_t)(col0 + brow1) * K_ + (kt) * 64 + bcol1,        \
                  &b_lds[buf][16384 + tid * 16]);                              \
  } while (0)

  STAGE(0, 0);
  __syncthreads();

  const int NKT = K_ / 64;   // 16
  for (int t = 0; t < NKT; ++t) {
    const int cur = t & 1;
    if (t + 1 < NKT) STAGE(t + 1, cur ^ 1);   // issue-early prefetch

#pragma unroll
    for (int kf = 0; kf < 2; ++kf) {
      short8 af[4], bfr[NW];
#pragma unroll
      for (int m = 0; m < 4; ++m) {
        int r = wm * 64 + m * 16 + l15;
        af[m] = *(const short8*)(&a_lds[cur][r * 128 +
                     ((kf * 64 + lhi * 16) ^ ((r & 7) << 4))]);
      }
#pragma unroll
      for (int n = 0; n < NW; ++n) {
        int r = wn * (16 * NW) + n * 16 + l15;
        bfr[n] = *(const short8*)(&b_lds[cur][r * 128 +
                     ((kf * 64 + lhi * 16) ^ ((r & 7) << 4))]);
      }

      __builtin_amdgcn_s_setprio(1);
#pragma unroll
      for (int m = 0; m < 4; ++m)
#pragma unroll
        for (int n = 0; n < NW; ++n)
          acc[m][n] = __builtin_amdgcn_mfma_f32_16x16x32_bf16(af[m], bfr[n],
                                                              acc[m][n], 0, 0, 0);
      __builtin_amdgcn_s_setprio(0);
    }

    __syncthreads();   // drains prefetch vmcnt + releases buffers
  }
#undef STAGE

  if (mode == 0) {
#pragma unroll
    for (int m = 0; m < 4; ++m) {
#pragma unroll
      for (int r = 0; r < 4; ++r) {
        int grow = row0 + wm * 64 + m * 16 + lhi * 4 + r;
        int b = grow >> 11, tt = grow & 2047;
#pragma unroll
        for (int n = 0; n < NW; ++n) {
          int gcol = col0 + wn * (16 * NW) + n * 16 + l15;
          float v = acc[m][n][r] + bias[gcol];
          int sel = gcol >> 10;
          int c1 = gcol & 1023;
          int hh = c1 >> 6, dh = c1 & 63;
          __hip_bfloat16 bv = __float2bfloat16(v);
          if (sel == 0)
            qdst[(((size_t)(b * H_ + hh)) * T_ + tt) * DH_ + dh] = bv;
          else if (sel == 1)
            kdst[(((size_t)(b * H_ + hh)) * T_ + tt) * DH_ + dh] = bv;
          else  // V stored transposed: [B,H,DH,T]
            vdst[(((size_t)(b * H_ + hh)) * DH_ + dh) * T_ + tt] = bv;
        }
      }
    }
  } else {
#pragma unroll
    for (int m = 0; m < 4; ++m) {
#pragma unroll
      for (int r = 0; r < 4; ++r) {
        int grow = row0 + wm * 64 + m * 16 + lhi * 4 + r;
#pragma unroll
        for (int n = 0; n < NW; ++n) {
          int gcol = col0 + wn * (16 * NW) + n * 16 + l15;
          fdst[(size_t)grow * C_ + gcol] = acc[m][n][r] + bias[gcol];
        }
      }
    }
  }
}

// ---------------- causal flash attention, LDS-staged K/V (8-wave reuse) -------
// R18: COMPLEMENTARY PAIRING. All 512 blocks are co-resident (2 blocks/CU:
// 36KB LDS, ~116 VGPR). Consecutive blocks (2i,2i+1) share a CU, so the
// balance unit is the PAIR: old decode gave both the same qb (worst CU =
// 2x32 tiles vs 36 avg -> ~52% util). New decode: j=blk>>1, bh=j&63,
// p=j>>6 (0..3); qb = (blk&1) ? 7-p : p  -> every CU hosts qb=p and 7-p
// = exactly 36 tile-units. Same coverage, same math.
__global__ __launch_bounds__(512, 2) void attn_kernel(
    const __hip_bfloat16* __restrict__ qg,
    const __hip_bfloat16* __restrict__ kg,
    const __hip_bfloat16* __restrict__ vtg,
    __hip_bfloat16* __restrict__ og)
{
  __shared__ char k_lds[2][8192];    // [buf][kv 64][dh 64] bf16, swz ((row&7)<<4)
  __shared__ char v_lds[2][8192];    // [buf][dh 64][kv 64] bf16 (V^T), same swz
  __shared__ char p_lds[8][4096];    // per-wave [32][64] bf16, swz ((row&7)<<4)

  const int tid = threadIdx.x;
  const int lane = tid & 63;
  const int w = tid >> 6;            // 0..7
  const int l15 = lane & 15;
  const int lhi = lane >> 4;
  const int blk = blockIdx.x;
  const int j2 = blk >> 1;
  const int bh = j2 & 63;
  const int p = j2 >> 6;             // 0..3
  const int qb = (blk & 1) ? (7 - p) : p;   // complementary pair per CU
  const int qr0 = qb * 256 + w * 32;
  const int nt = 4 * (qb + 1);
  const int tmask = qr0 >> 6;        // last tile this wave must compute

  const char* kpb = (const char*)(kg + (size_t)bh * T_ * DH_);
  const char* vtpb = (const char*)(vtg + (size_t)bh * DH_ * T_);
  const short* qp = (const short*)(qg + (size_t)bh * T_ * DH_);
  char* pwl = p_lds[w];

  const int srow = tid >> 3;
  const int scb = ((tid & 7) << 4) ^ ((srow & 7) << 4);
  const int sdst = tid * 16;

  short8 qf[2][2];
#pragma unroll
  for (int m = 0; m < 2; ++m)
#pragma unroll
    for (int kf = 0; kf < 2; ++kf)
      qf[m][kf] = *(const short8*)(qp + (size_t)(qr0 + m * 16 + l15) * DH_ +
                                   kf * 32 + lhi * 8);

  const f32x4 zf = {0.f, 0.f, 0.f, 0.f};
  f32x4 o[2][4];
  float lsum[2][4];
#pragma unroll
  for (int m = 0; m < 2; ++m) {
#pragma unroll
    for (int n = 0; n < 4; ++n) o[m][n] = zf;
#pragma unroll
    for (int r = 0; r < 4; ++r) lsum[m][r] = 0.f;
  }

  gload_lds16(kpb + (size_t)srow * 128 + scb, &k_lds[0][sdst]);
  gload_lds16(vtpb + (size_t)srow * 4096 + scb, &v_lds[0][sdst]);
  __syncthreads();

  for (int t = 0; t < nt; ++t) {
    const int cur = t & 1;
    if (t + 1 < nt) {
      const int kv1 = (t + 1) * 64;
      gload_lds16(kpb + (size_t)(kv1 + srow) * 128 + scb, &k_lds[cur ^ 1][sdst]);
      gload_lds16(vtpb + (size_t)srow * 4096 + kv1 * 2 + scb, &v_lds[cur ^ 1][sdst]);
    }

    if (t <= tmask) {
      const int kv0 = t * 64;

      short8 kfr[2][4];
#pragma unroll
      for (int kf = 0; kf < 2; ++kf)
#pragma unroll
        for (int n = 0; n < 4; ++n) {
          int kr = n * 16 + l15;
          kfr[kf][n] = *(const short8*)(&k_lds[cur][kr * 128 +
                           ((kf * 64 + lhi * 16) ^ ((kr & 7) << 4))]);
        }

      f32x4 s[2][4];
#pragma unroll
      for (int m = 0; m < 2; ++m)
#pragma unroll
        for (int n = 0; n < 4; ++n) s[m][n] = zf;
#pragma unroll
      for (int kf = 0; kf < 2; ++kf)
#pragma unroll
        for (int n = 0; n < 4; ++n)
#pragma unroll
          for (int m = 0; m < 2; ++m)
            s[m][n] = __builtin_amdgcn_mfma_f32_16x16x32_bf16(qf[m][kf], kfr[kf][n],
                                                              s[m][n], 0, 0, 0);

      short8 vfr[2][4];
#pragma unroll
      for (int kf = 0; kf < 2; ++kf)
#pragma unroll
        for (int n = 0; n < 4; ++n) {
          int vr = n * 16 + l15;
          vfr[kf][n] = *(const short8*)(&v_lds[cur][vr * 128 +
                           ((kf * 64 + lhi * 16) ^ ((vr & 7) << 4))]);
        }

      if (t == tmask) {
#pragma unroll
        for (int m = 0; m < 2; ++m)
#pragma unroll
          for (int n = 0; n < 4; ++n)
#pragma unroll
            for (int r = 0; r < 4; ++r) {
              int kvA = kv0 + n * 16 + l15;
              int qA = qr0 + m * 16 + lhi * 4 + r;
              if (kvA > qA) s[m][n][r] = -1e30f;
            }
      }

#pragma unroll
      for (int m = 0; m < 2; ++m)
#pragma unroll
        for (int n = 0; n < 4; ++n)
#pragma unroll
          for (int r = 0; r < 4; ++r) {
            float pe = __expf(s[m][n][r] * 0.125f);
            s[m][n][r] = pe;
            lsum[m][r] += pe;
          }

#pragma unroll
      for (int m = 0; m < 2; ++m)
#pragma unroll
        for (int n = 0; n < 4; ++n)
#pragma unroll
          for (int r = 0; r < 4; ++r) {
            int row = m * 16 + lhi * 4 + r;
            *(unsigned short*)(pwl + row * 128 +
                               (((n * 16 + l15) * 2) ^ ((row & 7) << 4))) =
                f2b(s[m][n][r]);
          }
      short8 pa[2][2];
#pragma unroll
      for (int m = 0; m < 2; ++m)
#pragma unroll
        for (int kf = 0; kf < 2; ++kf) {
          int row = m * 16 + l15;
          pa[m][kf] = *(const short8*)(pwl + row * 128 +
                                       ((kf * 64 + lhi * 16) ^ ((row & 7) << 4)));
        }

#pragma unroll
      for (int kf = 0; kf < 2; ++kf)
#pragma unroll
        for (int n = 0; n < 4; ++n)
#pragma unroll
          for (int m = 0; m < 2; ++m)
            o[m][n] = __builtin_amdgcn_mfma_f32_16x16x32_bf16(pa[m][kf], vfr[kf][n],
                                                              o[m][n], 0, 0, 0);
    }

    __syncthreads();
  }

#pragma unroll
  for (int m = 0; m < 2; ++m)
#pragma unroll
    for (int r = 0; r < 4; ++r)
#pragma unroll
      for (int d = 1; d < 16; d <<= 1)
        lsum[m][r] += __shfl_xor(lsum[m][r], d, 64);

  const int b = bh >> 4, hd = bh & 15;
#pragma unroll
  for (int m = 0; m < 2; ++m)
#pragma unroll
    for (int r = 0; r < 4; ++r) {
      float inv = 1.f / lsum[m][r];
      int qrow = qr0 + m * 16 + lhi * 4 + r;
      __hip_bfloat16* orow = og + ((size_t)(b * T_ + qrow)) * C_ + hd * DH_;
#pragma unroll
      for (int n = 0; n < 4; ++n)
        orow[n * 16 + l15] = __float2bfloat16(o[m][n][r] * inv);
    }
}

// ---------------- launch ----------------
extern "C" void kernel_launch(void* const* d_in, const int* in_sizes, int n_in,
                              void* d_out, int out_size, void* d_ws, size_t ws_size,
                              hipStream_t stream) {
  const float* x      = (const float*)d_in[0];
  const float* qkv_w  = (const float*)d_in[1];
  const float* qkv_b  = (const float*)d_in[2];
  const float* proj_w = (const float*)d_in[3];
  const float* proj_b = (const float*)d_in[4];
  float* out = (float*)d_out;

  char* ws = (char*)d_ws;
  __hip_bfloat16* xb    = (__hip_bfloat16*)(ws);                 // 16 MB
  __hip_bfloat16* wqkv  = (__hip_bfloat16*)(ws + 16777216);      // 6 MB
  __hip_bfloat16* wproj = (__hip_bfloat16*)(ws + 23068672);      // 2 MB
  __hip_bfloat16* qb    = (__hip_bfloat16*)(ws + 25165824);      // 16 MB
  __hip_bfloat16* kb    = (__hip_bfloat16*)(ws + 41943040);      // 16 MB
  __hip_bfloat16* vtb   = (__hip_bfloat16*)(ws + 58720256);      // 16 MB (V^T)
  __hip_bfloat16* att   = (__hip_bfloat16*)(ws + 75497472);      // 16 MB

  cvt_all<<<2048, 256, 0, stream>>>(x, qkv_w, proj_w, xb, wqkv, wproj);

  // QKV: tile 256x192, grid 16x32 = 512 = 2 balanced rounds; bx-major decode
  gemm_bt<3><<<dim3((M_/256) * (NQKV_/192)), 1024, 0, stream>>>(
      xb, wqkv, qkv_b, 0, NQKV_/192, qb, kb, vtb, nullptr);

  attn_kernel<<<dim3(512), 512, 0, stream>>>(qb, kb, vtb, att);

  // proj: tile 256x128, grid 8x32 = 256 = exactly 1 full-chip round; bx-major
  gemm_bt<2><<<dim3((M_/256) * (C_/128)), 1024, 0, stream>>>(
      att, wproj, proj_b, 1, C_/128, nullptr, nullptr, nullptr, out);
}

// Round 19
// 214.578 us; speedup vs baseline: 1.0117x; 1.0117x over previous
//
#include <hip/hip_runtime.h>
#include <hip/hip_bf16.h>
#include <stdint.h>

#define B_ 4
#define T_ 2048
#define C_ 1024
#define H_ 16
#define DH_ 64
#define M_ (B_*T_)      // 8192
#define NQKV_ (3*C_)    // 3072
#define K_ C_           // 1024

typedef __attribute__((ext_vector_type(8))) short short8;
typedef __attribute__((ext_vector_type(4))) float f32x4;
typedef __attribute__((ext_vector_type(4))) unsigned short us4;

union BFC { __hip_bfloat16 h; unsigned short u; };
__device__ inline unsigned short f2b(float f){ BFC c; c.h = __float2bfloat16(f); return c.u; }

__device__ inline void gload_lds16(const void* g, void* l){
  __builtin_amdgcn_global_load_lds(
    (const __attribute__((address_space(1))) void*)(uintptr_t)g,
    (__attribute__((address_space(3))) void*)(uintptr_t)l,
    16, 0, 0);
}

// ---------------- fused fp32 -> bf16 convert (x, qkv_w, proj_w) ----------------
__global__ void cvt_all(const float* __restrict__ x,
                        const float* __restrict__ qw,
                        const float* __restrict__ pw,
                        __hip_bfloat16* __restrict__ xb,
                        __hip_bfloat16* __restrict__ qwb,
                        __hip_bfloat16* __restrict__ pwb)
{
  const int NX = M_ * K_ / 4;          // 2,097,152 float4
  const int NQ = NQKV_ * K_ / 4;       //   786,432
  const int NP = C_ * K_ / 4;          //   262,144
  int i = blockIdx.x * blockDim.x + threadIdx.x;
  int stride = gridDim.x * blockDim.x;
  for (; i < NX + NQ + NP; i += stride) {
    const float4* s;
    us4* d;
    int j = i;
    if (j < NX)            { s = (const float4*)x  + j; d = (us4*)xb  + j; }
    else if (j < NX + NQ)  { j -= NX; s = (const float4*)qw + j; d = (us4*)qwb + j; }
    else                   { j -= NX + NQ; s = (const float4*)pw + j; d = (us4*)pwb + j; }
    float4 v = *s;
    us4 o;
    o.x = f2b(v.x); o.y = f2b(v.y); o.z = f2b(v.z); o.w = f2b(v.w);
    *d = o;
  }
}

// ---------------- GEMM: Y[M,N] = A[M,K] * B[N,K]^T + bias ----------------
// (R16 keeper, unchanged: 91.5us qkv / ~21us proj)
// Tile 256 x (64*NW), 1024 thr = 16 waves (4x4), per-wave 64 x (16*NW).
// BK=64, rows 128 B, proven swizzle ((r&7)<<4) both sides (0 conflicts).
// bx-MAJOR decode. 2-phase issue-early prefetch + one syncthreads/K-step.
template<int NW>
__global__ __launch_bounds__(1024) void gemm_bt(
    const __hip_bfloat16* __restrict__ A,
    const __hip_bfloat16* __restrict__ Bw,
    const float* __restrict__ bias,
    int mode, int nbx,
    __hip_bfloat16* __restrict__ qdst,
    __hip_bfloat16* __restrict__ kdst,
    __hip_bfloat16* __restrict__ vdst,
    float* __restrict__ fdst)
{
  __shared__ char a_lds[2][32768];        // 256 rows x 128 B, swz ((r&7)<<4)
  __shared__ char b_lds[2][NW * 8192];    // 64*NW rows x 128 B

  const int tid = threadIdx.x;            // 0..1023
  const int lane = tid & 63;
  const int w = tid >> 6;                 // 0..15
  const int l15 = lane & 15;
  const int lhi = lane >> 4;
  const int wm = w >> 2, wn = w & 3;      // wave grid 4 x 4

  const int nwg = gridDim.x;
  const int q8 = nwg >> 3;
  const int lb = (blockIdx.x & 7) * q8 + (blockIdx.x >> 3);
  const int bx = lb % nbx, by = lb / nbx;   // bx-major (A panels L2-resident)
  const int row0 = by * 256;
  const int col0 = bx * (64 * NW);

  int arow[2], acol[2];
#pragma unroll
  for (int i = 0; i < 2; ++i) {
    int L = i * 16384 + tid * 16;
    int r = L >> 7;
    int cb = (L & 127) ^ ((r & 7) << 4);
    arow[i] = r; acol[i] = cb >> 1;
  }
  int brow0, bcol0, brow1 = 0, bcol1 = 0;
  {
    int L = tid * 16;
    int r = L >> 7;
    int cb = (L & 127) ^ ((r & 7) << 4);
    brow0 = r; bcol0 = cb >> 1;
  }
  const bool b1act = (NW == 4) || (NW == 3 && tid < 512);
  if (b1act) {
    int L = 16384 + tid * 16;
    int r = L >> 7;
    int cb = (L & 127) ^ ((r & 7) << 4);
    brow1 = r; bcol1 = cb >> 1;
  }

  const f32x4 zf = {0.f, 0.f, 0.f, 0.f};
  f32x4 acc[4][NW];
#pragma unroll
  for (int m = 0; m < 4; ++m)
#pragma unroll
    for (int n = 0; n < NW; ++n) acc[m][n] = zf;

  const short* Ag = (const short*)A;
  const short* Bg = (const short*)Bw;

#define STAGE(kt, buf)                                                         \
  do {                                                                         \
    gload_lds16(Ag + (size_t)(row0 + arow[0]) * K_ + (kt) * 64 + acol[0],      \
                &a_lds[buf][tid * 16]);                                        \
    gload_lds16(Ag + (size_t)(row0 + arow[1]) * K_ + (kt) * 64 + acol[1],      \
                &a_lds[buf][16384 + tid * 16]);                                \
    gload_lds16(Bg + (size_t)(col0 + brow0) * K_ + (kt) * 64 + bcol0,          \
                &b_lds[buf][tid * 16]);                                        \
    if (b1act)                                                                 \
      gload_lds16(Bg + (size_t)(col0 + brow1) * K_ + (kt) * 64 + bcol1,        \
                  &b_lds[buf][16384 + tid * 16]);                              \
  } while (0)

  STAGE(0, 0);
  __syncthreads();

  const int NKT = K_ / 64;   // 16
  for (int t = 0; t < NKT; ++t) {
    const int cur = t & 1;
    if (t + 1 < NKT) STAGE(t + 1, cur ^ 1);   // issue-early prefetch

#pragma unroll
    for (int kf = 0; kf < 2; ++kf) {
      short8 af[4], bfr[NW];
#pragma unroll
      for (int m = 0; m < 4; ++m) {
        int r = wm * 64 + m * 16 + l15;
        af[m] = *(const short8*)(&a_lds[cur][r * 128 +
                     ((kf * 64 + lhi * 16) ^ ((r & 7) << 4))]);
      }
#pragma unroll
      for (int n = 0; n < NW; ++n) {
        int r = wn * (16 * NW) + n * 16 + l15;
        bfr[n] = *(const short8*)(&b_lds[cur][r * 128 +
                     ((kf * 64 + lhi * 16) ^ ((r & 7) << 4))]);
      }

      __builtin_amdgcn_s_setprio(1);
#pragma unroll
      for (int m = 0; m < 4; ++m)
#pragma unroll
        for (int n = 0; n < NW; ++n)
          acc[m][n] = __builtin_amdgcn_mfma_f32_16x16x32_bf16(af[m], bfr[n],
                                                              acc[m][n], 0, 0, 0);
      __builtin_amdgcn_s_setprio(0);
    }

    __syncthreads();   // drains prefetch vmcnt + releases buffers
  }
#undef STAGE

  if (mode == 0) {
#pragma unroll
    for (int m = 0; m < 4; ++m) {
#pragma unroll
      for (int r = 0; r < 4; ++r) {
        int grow = row0 + wm * 64 + m * 16 + lhi * 4 + r;
        int b = grow >> 11, tt = grow & 2047;
#pragma unroll
        for (int n = 0; n < NW; ++n) {
          int gcol = col0 + wn * (16 * NW) + n * 16 + l15;
          float v = acc[m][n][r] + bias[gcol];
          int sel = gcol >> 10;
          int c1 = gcol & 1023;
          int hh = c1 >> 6, dh = c1 & 63;
          __hip_bfloat16 bv = __float2bfloat16(v);
          if (sel == 0)
            qdst[(((size_t)(b * H_ + hh)) * T_ + tt) * DH_ + dh] = bv;
          else if (sel == 1)
            kdst[(((size_t)(b * H_ + hh)) * T_ + tt) * DH_ + dh] = bv;
          else  // V stored transposed: [B,H,DH,T]
            vdst[(((size_t)(b * H_ + hh)) * DH_ + dh) * T_ + tt] = bv;
        }
      }
    }
  } else {
#pragma unroll
    for (int m = 0; m < 4; ++m) {
#pragma unroll
      for (int r = 0; r < 4; ++r) {
        int grow = row0 + wm * 64 + m * 16 + lhi * 4 + r;
#pragma unroll
        for (int n = 0; n < NW; ++n) {
          int gcol = col0 + wn * (16 * NW) + n * 16 + l15;
          fdst[(size_t)grow * C_ + gcol] = acc[m][n][r] + bias[gcol];
        }
      }
    }
  }
}

// ---------------- causal flash attention, LDS-staged K/V (8-wave reuse) -------
// R19 decode: respects XCD round-robin (blk%8 = XCD, measured R18: violating
// it gave 2.6x XCD imbalance + 8MB/XCD K/V thrash, 28->108us).
//   x = blk&7 (XCD), j = blk>>3 (pos in XCD), c = j>>1, e = j&1
//   bh = x + 8*(c&7)   -> head still XCD-local (8 heads x 512KB = 4MB = L2)
//   qb = e ? 7-(c>>3) : (c>>3)  -> adjacent-in-XCD blocks are complements:
//        if within-XCD placement is sequential, every CU hosts qb=p & 7-p
//        (36 tile-units); if not, still perfectly XCD-balanced (= R16 floor).
__global__ __launch_bounds__(512, 2) void attn_kernel(
    const __hip_bfloat16* __restrict__ qg,
    const __hip_bfloat16* __restrict__ kg,
    const __hip_bfloat16* __restrict__ vtg,
    __hip_bfloat16* __restrict__ og)
{
  __shared__ char k_lds[2][8192];    // [buf][kv 64][dh 64] bf16, swz ((row&7)<<4)
  __shared__ char v_lds[2][8192];    // [buf][dh 64][kv 64] bf16 (V^T), same swz
  __shared__ char p_lds[8][4096];    // per-wave [32][64] bf16, swz ((row&7)<<4)

  const int tid = threadIdx.x;
  const int lane = tid & 63;
  const int w = tid >> 6;            // 0..7
  const int l15 = lane & 15;
  const int lhi = lane >> 4;
  const int blk = blockIdx.x;
  const int x = blk & 7;             // XCD
  const int j = blk >> 3;            // 0..63 position within XCD
  const int c = j >> 1;              // 0..31
  const int e = j & 1;
  const int bh = x + 8 * (c & 7);    // head, bh%8 == x (XCD-local K/V)
  const int qb = e ? (7 - (c >> 3)) : (c >> 3);
  const int qr0 = qb * 256 + w * 32;
  const int nt = 4 * (qb + 1);
  const int tmask = qr0 >> 6;        // last tile this wave must compute

  const char* kpb = (const char*)(kg + (size_t)bh * T_ * DH_);
  const char* vtpb = (const char*)(vtg + (size_t)bh * DH_ * T_);
  const short* qp = (const short*)(qg + (size_t)bh * T_ * DH_);
  char* pwl = p_lds[w];

  const int srow = tid >> 3;
  const int scb = ((tid & 7) << 4) ^ ((srow & 7) << 4);
  const int sdst = tid * 16;

  short8 qf[2][2];
#pragma unroll
  for (int m = 0; m < 2; ++m)
#pragma unroll
    for (int kf = 0; kf < 2; ++kf)
      qf[m][kf] = *(const short8*)(qp + (size_t)(qr0 + m * 16 + l15) * DH_ +
                                   kf * 32 + lhi * 8);

  const f32x4 zf = {0.f, 0.f, 0.f, 0.f};
  f32x4 o[2][4];
  float lsum[2][4];
#pragma unroll
  for (int m = 0; m < 2; ++m) {
#pragma unroll
    for (int n = 0; n < 4; ++n) o[m][n] = zf;
#pragma unroll
    for (int r = 0; r < 4; ++r) lsum[m][r] = 0.f;
  }

  gload_lds16(kpb + (size_t)srow * 128 + scb, &k_lds[0][sdst]);
  gload_lds16(vtpb + (size_t)srow * 4096 + scb, &v_lds[0][sdst]);
  __syncthreads();

  for (int t = 0; t < nt; ++t) {
    const int cur = t & 1;
    if (t + 1 < nt) {
      const int kv1 = (t + 1) * 64;
      gload_lds16(kpb + (size_t)(kv1 + srow) * 128 + scb, &k_lds[cur ^ 1][sdst]);
      gload_lds16(vtpb + (size_t)srow * 4096 + kv1 * 2 + scb, &v_lds[cur ^ 1][sdst]);
    }

    if (t <= tmask) {
      const int kv0 = t * 64;

      short8 kfr[2][4];
#pragma unroll
      for (int kf = 0; kf < 2; ++kf)
#pragma unroll
        for (int n = 0; n < 4; ++n) {
          int kr = n * 16 + l15;
          kfr[kf][n] = *(const short8*)(&k_lds[cur][kr * 128 +
                           ((kf * 64 + lhi * 16) ^ ((kr & 7) << 4))]);
        }

      f32x4 s[2][4];
#pragma unroll
      for (int m = 0; m < 2; ++m)
#pragma unroll
        for (int n = 0; n < 4; ++n) s[m][n] = zf;
#pragma unroll
      for (int kf = 0; kf < 2; ++kf)
#pragma unroll
        for (int n = 0; n < 4; ++n)
#pragma unroll
          for (int m = 0; m < 2; ++m)
            s[m][n] = __builtin_amdgcn_mfma_f32_16x16x32_bf16(qf[m][kf], kfr[kf][n],
                                                              s[m][n], 0, 0, 0);

      short8 vfr[2][4];
#pragma unroll
      for (int kf = 0; kf < 2; ++kf)
#pragma unroll
        for (int n = 0; n < 4; ++n) {
          int vr = n * 16 + l15;
          vfr[kf][n] = *(const short8*)(&v_lds[cur][vr * 128 +
                           ((kf * 64 + lhi * 16) ^ ((vr & 7) << 4))]);
        }

      if (t == tmask) {
#pragma unroll
        for (int m = 0; m < 2; ++m)
#pragma unroll
          for (int n = 0; n < 4; ++n)
#pragma unroll
            for (int r = 0; r < 4; ++r) {
              int kvA = kv0 + n * 16 + l15;
              int qA = qr0 + m * 16 + lhi * 4 + r;
              if (kvA > qA) s[m][n][r] = -1e30f;
            }
      }

#pragma unroll
      for (int m = 0; m < 2; ++m)
#pragma unroll
        for (int n = 0; n < 4; ++n)
#pragma unroll
          for (int r = 0; r < 4; ++r) {
            float pe = __expf(s[m][n][r] * 0.125f);
            s[m][n][r] = pe;
            lsum[m][r] += pe;
          }

#pragma unroll
      for (int m = 0; m < 2; ++m)
#pragma unroll
        for (int n = 0; n < 4; ++n)
#pragma unroll
          for (int r = 0; r < 4; ++r) {
            int row = m * 16 + lhi * 4 + r;
            *(unsigned short*)(pwl + row * 128 +
                               (((n * 16 + l15) * 2) ^ ((row & 7) << 4))) =
                f2b(s[m][n][r]);
          }
      short8 pa[2][2];
#pragma unroll
      for (int m = 0; m < 2; ++m)
#pragma unroll
        for (int kf = 0; kf < 2; ++kf) {
          int row = m * 16 + l15;
          pa[m][kf] = *(const short8*)(pwl + row * 128 +
                                       ((kf * 64 + lhi * 16) ^ ((row & 7) << 4)));
        }

#pragma unroll
      for (int kf = 0; kf < 2; ++kf)
#pragma unroll
        for (int n = 0; n < 4; ++n)
#pragma unroll
          for (int m = 0; m < 2; ++m)
            o[m][n] = __builtin_amdgcn_mfma_f32_16x16x32_bf16(pa[m][kf], vfr[kf][n],
                                                              o[m][n], 0, 0, 0);
    }

    __syncthreads();
  }

#pragma unroll
  for (int m = 0; m < 2; ++m)
#pragma unroll
    for (int r = 0; r < 4; ++r)
#pragma unroll
      for (int d = 1; d < 16; d <<= 1)
        lsum[m][r] += __shfl_xor(lsum[m][r], d, 64);

  const int b = bh >> 4, hd = bh & 15;
#pragma unroll
  for (int m = 0; m < 2; ++m)
#pragma unroll
    for (int r = 0; r < 4; ++r) {
      float inv = 1.f / lsum[m][r];
      int qrow = qr0 + m * 16 + lhi * 4 + r;
      __hip_bfloat16* orow = og + ((size_t)(b * T_ + qrow)) * C_ + hd * DH_;
#pragma unroll
      for (int n = 0; n < 4; ++n)
        orow[n * 16 + l15] = __float2bfloat16(o[m][n][r] * inv);
    }
}

// ---------------- launch ----------------
extern "C" void kernel_launch(void* const* d_in, const int* in_sizes, int n_in,
                              void* d_out, int out_size, void* d_ws, size_t ws_size,
                              hipStream_t stream) {
  const float* x      = (const float*)d_in[0];
  const float* qkv_w  = (const float*)d_in[1];
  const float* qkv_b  = (const float*)d_in[2];
  const float* proj_w = (const float*)d_in[3];
  const float* proj_b = (const float*)d_in[4];
  float* out = (float*)d_out;

  char* ws = (char*)d_ws;
  __hip_bfloat16* xb    = (__hip_bfloat16*)(ws);                 // 16 MB
  __hip_bfloat16* wqkv  = (__hip_bfloat16*)(ws + 16777216);      // 6 MB
  __hip_bfloat16* wproj = (__hip_bfloat16*)(ws + 23068672);      // 2 MB
  __hip_bfloat16* qb    = (__hip_bfloat16*)(ws + 25165824);      // 16 MB
  __hip_bfloat16* kb    = (__hip_bfloat16*)(ws + 41943040);      // 16 MB
  __hip_bfloat16* vtb   = (__hip_bfloat16*)(ws + 58720256);      // 16 MB (V^T)
  __hip_bfloat16* att   = (__hip_bfloat16*)(ws + 75497472);      // 16 MB

  cvt_all<<<2048, 256, 0, stream>>>(x, qkv_w, proj_w, xb, wqkv, wproj);

  // QKV: tile 256x192, grid 16x32 = 512 = 2 balanced rounds; bx-major decode
  gemm_bt<3><<<dim3((M_/256) * (NQKV_/192)), 1024, 0, stream>>>(
      xb, wqkv, qkv_b, 0, NQKV_/192, qb, kb, vtb, nullptr);

  attn_kernel<<<dim3(512), 512, 0, stream>>>(qb, kb, vtb, att);

  // proj: tile 256x128, grid 8x32 = 256 = exactly 1 full-chip round; bx-major
  gemm_bt<2><<<dim3((M_/256) * (C_/128)), 1024, 0, stream>>>(
      att, wproj, proj_b, 1, C_/128, nullptr, nullptr, nullptr, out);
}

// Round 20
// 188.687 us; speedup vs baseline: 1.1506x; 1.1372x over previous
//
#include <hip/hip_runtime.h>
#include <hip/hip_bf16.h>
#include <stdint.h>

#define B_ 4
#define T_ 2048
#define C_ 1024
#define H_ 16
#define DH_ 64
#define M_ (B_*T_)      // 8192
#define NQKV_ (3*C_)    // 3072
#define K_ C_           // 1024

typedef __attribute__((ext_vector_type(8))) short short8;
typedef __attribute__((ext_vector_type(4))) float f32x4;
typedef __attribute__((ext_vector_type(4))) unsigned short us4;

union BFC { __hip_bfloat16 h; unsigned short u; };
__device__ inline unsigned short f2b(float f){ BFC c; c.h = __float2bfloat16(f); return c.u; }

__device__ inline void gload_lds16(const void* g, void* l){
  __builtin_amdgcn_global_load_lds(
    (const __attribute__((address_space(1))) void*)(uintptr_t)g,
    (__attribute__((address_space(3))) void*)(uintptr_t)l,
    16, 0, 0);
}

// ---------------- fused fp32 -> bf16 convert (x, qkv_w, proj_w) ----------------
__global__ void cvt_all(const float* __restrict__ x,
                        const float* __restrict__ qw,
                        const float* __restrict__ pw,
                        __hip_bfloat16* __restrict__ xb,
                        __hip_bfloat16* __restrict__ qwb,
                        __hip_bfloat16* __restrict__ pwb)
{
  const int NX = M_ * K_ / 4;          // 2,097,152 float4
  const int NQ = NQKV_ * K_ / 4;       //   786,432
  const int NP = C_ * K_ / 4;          //   262,144
  int i = blockIdx.x * blockDim.x + threadIdx.x;
  int stride = gridDim.x * blockDim.x;
  for (; i < NX + NQ + NP; i += stride) {
    const float4* s;
    us4* d;
    int j = i;
    if (j < NX)            { s = (const float4*)x  + j; d = (us4*)xb  + j; }
    else if (j < NX + NQ)  { j -= NX; s = (const float4*)qw + j; d = (us4*)qwb + j; }
    else                   { j -= NX + NQ; s = (const float4*)pw + j; d = (us4*)pwb + j; }
    float4 v = *s;
    us4 o;
    o.x = f2b(v.x); o.y = f2b(v.y); o.z = f2b(v.z); o.w = f2b(v.w);
    *d = o;
  }
}

// ---------------- GEMM: Y[M,N] = A[M,K] * B[N,K]^T + bias ----------------
// (R16 keeper: 91.5us qkv / proj near floor)
// Tile 256 x (64*NW), 1024 thr = 16 waves (4x4), per-wave 64 x (16*NW).
// BK=64, rows 128 B, proven swizzle ((r&7)<<4) both sides (0 conflicts).
// bx-MAJOR decode (by-major streams all of A through each XCD L2: +133% fetch).
// 2-phase issue-early prefetch + one syncthreads per K-step. Schedule variants
// (counted-vmcnt ring, 8-phase, quad-buffer) all measured neutral-or-worse:
// this 16-wave/1-block-per-CU structure is at its LDS-issue/staging plateau.
template<int NW>
__global__ __launch_bounds__(1024) void gemm_bt(
    const __hip_bfloat16* __restrict__ A,
    const __hip_bfloat16* __restrict__ Bw,
    const float* __restrict__ bias,
    int mode, int nbx,
    __hip_bfloat16* __restrict__ qdst,
    __hip_bfloat16* __restrict__ kdst,
    __hip_bfloat16* __restrict__ vdst,
    float* __restrict__ fdst)
{
  __shared__ char a_lds[2][32768];        // 256 rows x 128 B, swz ((r&7)<<4)
  __shared__ char b_lds[2][NW * 8192];    // 64*NW rows x 128 B

  const int tid = threadIdx.x;            // 0..1023
  const int lane = tid & 63;
  const int w = tid >> 6;                 // 0..15
  const int l15 = lane & 15;
  const int lhi = lane >> 4;
  const int wm = w >> 2, wn = w & 3;      // wave grid 4 x 4

  const int nwg = gridDim.x;
  const int q8 = nwg >> 3;
  const int lb = (blockIdx.x & 7) * q8 + (blockIdx.x >> 3);
  const int bx = lb % nbx, by = lb / nbx;   // bx-major (A panels L2-resident)
  const int row0 = by * 256;
  const int col0 = bx * (64 * NW);

  int arow[2], acol[2];
#pragma unroll
  for (int i = 0; i < 2; ++i) {
    int L = i * 16384 + tid * 16;
    int r = L >> 7;
    int cb = (L & 127) ^ ((r & 7) << 4);
    arow[i] = r; acol[i] = cb >> 1;
  }
  int brow0, bcol0, brow1 = 0, bcol1 = 0;
  {
    int L = tid * 16;
    int r = L >> 7;
    int cb = (L & 127) ^ ((r & 7) << 4);
    brow0 = r; bcol0 = cb >> 1;
  }
  const bool b1act = (NW == 4) || (NW == 3 && tid < 512);
  if (b1act) {
    int L = 16384 + tid * 16;
    int r = L >> 7;
    int cb = (L & 127) ^ ((r & 7) << 4);
    brow1 = r; bcol1 = cb >> 1;
  }

  const f32x4 zf = {0.f, 0.f, 0.f, 0.f};
  f32x4 acc[4][NW];
#pragma unroll
  for (int m = 0; m < 4; ++m)
#pragma unroll
    for (int n = 0; n < NW; ++n) acc[m][n] = zf;

  const short* Ag = (const short*)A;
  const short* Bg = (const short*)Bw;

#define STAGE(kt, buf)                                                         \
  do {                                                                         \
    gload_lds16(Ag + (size_t)(row0 + arow[0]) * K_ + (kt) * 64 + acol[0],      \
                &a_lds[buf][tid * 16]);                                        \
    gload_lds16(Ag + (size_t)(row0 + arow[1]) * K_ + (kt) * 64 + acol[1],      \
                &a_lds[buf][16384 + tid * 16]);                                \
    gload_lds16(Bg + (size_t)(col0 + brow0) * K_ + (kt) * 64 + bcol0,          \
                &b_lds[buf][tid * 16]);                                        \
    if (b1act)                                                                 \
      gload_lds16(Bg + (size_t)(col0 + brow1) * K_ + (kt) * 64 + bcol1,        \
                  &b_lds[buf][16384 + tid * 16]);                              \
  } while (0)

  STAGE(0, 0);
  __syncthreads();

  const int NKT = K_ / 64;   // 16
  for (int t = 0; t < NKT; ++t) {
    const int cur = t & 1;
    if (t + 1 < NKT) STAGE(t + 1, cur ^ 1);   // issue-early prefetch

#pragma unroll
    for (int kf = 0; kf < 2; ++kf) {
      short8 af[4], bfr[NW];
#pragma unroll
      for (int m = 0; m < 4; ++m) {
        int r = wm * 64 + m * 16 + l15;
        af[m] = *(const short8*)(&a_lds[cur][r * 128 +
                     ((kf * 64 + lhi * 16) ^ ((r & 7) << 4))]);
      }
#pragma unroll
      for (int n = 0; n < NW; ++n) {
        int r = wn * (16 * NW) + n * 16 + l15;
        bfr[n] = *(const short8*)(&b_lds[cur][r * 128 +
                     ((kf * 64 + lhi * 16) ^ ((r & 7) << 4))]);
      }

      __builtin_amdgcn_s_setprio(1);
#pragma unroll
      for (int m = 0; m < 4; ++m)
#pragma unroll
        for (int n = 0; n < NW; ++n)
          acc[m][n] = __builtin_amdgcn_mfma_f32_16x16x32_bf16(af[m], bfr[n],
                                                              acc[m][n], 0, 0, 0);
      __builtin_amdgcn_s_setprio(0);
    }

    __syncthreads();   // drains prefetch vmcnt + releases buffers
  }
#undef STAGE

  if (mode == 0) {
#pragma unroll
    for (int m = 0; m < 4; ++m) {
#pragma unroll
      for (int r = 0; r < 4; ++r) {
        int grow = row0 + wm * 64 + m * 16 + lhi * 4 + r;
        int b = grow >> 11, tt = grow & 2047;
#pragma unroll
        for (int n = 0; n < NW; ++n) {
          int gcol = col0 + wn * (16 * NW) + n * 16 + l15;
          float v = acc[m][n][r] + bias[gcol];
          int sel = gcol >> 10;
          int c1 = gcol & 1023;
          int hh = c1 >> 6, dh = c1 & 63;
          __hip_bfloat16 bv = __float2bfloat16(v);
          if (sel == 0)
            qdst[(((size_t)(b * H_ + hh)) * T_ + tt) * DH_ + dh] = bv;
          else if (sel == 1)
            kdst[(((size_t)(b * H_ + hh)) * T_ + tt) * DH_ + dh] = bv;
          else  // V stored transposed: [B,H,DH,T]
            vdst[(((size_t)(b * H_ + hh)) * DH_ + dh) * T_ + tt] = bv;
        }
      }
    }
  } else {
#pragma unroll
    for (int m = 0; m < 4; ++m) {
#pragma unroll
      for (int r = 0; r < 4; ++r) {
        int grow = row0 + wm * 64 + m * 16 + lhi * 4 + r;
#pragma unroll
        for (int n = 0; n < NW; ++n) {
          int gcol = col0 + wn * (16 * NW) + n * 16 + l15;
          fdst[(size_t)grow * C_ + gcol] = acc[m][n][r] + bias[gcol];
        }
      }
    }
  }
}

// ---------------- causal flash attention, LDS-staged K/V (8-wave reuse) -------
// R16 decode RESTORED. Under the measured dispatch model (blk%8 = XCD;
// within-XCD placement one-per-CU in rounds), this decode gives CU k the
// pair (qb=g, qb=7-g) = exactly 36 tile-units on EVERY CU - already the
// optimal complementary pairing. R17-R19 remaps all regressed (28->107us):
// do not touch bh/qb decode without re-deriving both XCD and CU placement.
__global__ __launch_bounds__(512, 2) void attn_kernel(
    const __hip_bfloat16* __restrict__ qg,
    const __hip_bfloat16* __restrict__ kg,
    const __hip_bfloat16* __restrict__ vtg,
    __hip_bfloat16* __restrict__ og)
{
  __shared__ char k_lds[2][8192];    // [buf][kv 64][dh 64] bf16, swz ((row&7)<<4)
  __shared__ char v_lds[2][8192];    // [buf][dh 64][kv 64] bf16 (V^T), same swz
  __shared__ char p_lds[8][4096];    // per-wave [32][64] bf16, swz ((row&7)<<4)

  const int tid = threadIdx.x;
  const int lane = tid & 63;
  const int w = tid >> 6;            // 0..7
  const int l15 = lane & 15;
  const int lhi = lane >> 4;
  const int blk = blockIdx.x;
  const int bh = blk & 63;           // same-head blocks share XCD (blk%8 == bh%8)
  const int g = blk >> 6;            // 0..7
  const int qb = (g < 4) ? g : 11 - g;  // CU pair = (g, 7-g) = 36 tile-units
  const int qr0 = qb * 256 + w * 32;
  const int nt = 4 * (qb + 1);
  const int tmask = qr0 >> 6;        // last tile this wave must compute

  const char* kpb = (const char*)(kg + (size_t)bh * T_ * DH_);
  const char* vtpb = (const char*)(vtg + (size_t)bh * DH_ * T_);
  const short* qp = (const short*)(qg + (size_t)bh * T_ * DH_);
  char* pwl = p_lds[w];

  const int srow = tid >> 3;
  const int scb = ((tid & 7) << 4) ^ ((srow & 7) << 4);
  const int sdst = tid * 16;

  short8 qf[2][2];
#pragma unroll
  for (int m = 0; m < 2; ++m)
#pragma unroll
    for (int kf = 0; kf < 2; ++kf)
      qf[m][kf] = *(const short8*)(qp + (size_t)(qr0 + m * 16 + l15) * DH_ +
                                   kf * 32 + lhi * 8);

  const f32x4 zf = {0.f, 0.f, 0.f, 0.f};
  f32x4 o[2][4];
  float lsum[2][4];
#pragma unroll
  for (int m = 0; m < 2; ++m) {
#pragma unroll
    for (int n = 0; n < 4; ++n) o[m][n] = zf;
#pragma unroll
    for (int r = 0; r < 4; ++r) lsum[m][r] = 0.f;
  }

  gload_lds16(kpb + (size_t)srow * 128 + scb, &k_lds[0][sdst]);
  gload_lds16(vtpb + (size_t)srow * 4096 + scb, &v_lds[0][sdst]);
  __syncthreads();

  for (int t = 0; t < nt; ++t) {
    const int cur = t & 1;
    if (t + 1 < nt) {
      const int kv1 = (t + 1) * 64;
      gload_lds16(kpb + (size_t)(kv1 + srow) * 128 + scb, &k_lds[cur ^ 1][sdst]);
      gload_lds16(vtpb + (size_t)srow * 4096 + kv1 * 2 + scb, &v_lds[cur ^ 1][sdst]);
    }

    if (t <= tmask) {
      const int kv0 = t * 64;

      short8 kfr[2][4];
#pragma unroll
      for (int kf = 0; kf < 2; ++kf)
#pragma unroll
        for (int n = 0; n < 4; ++n) {
          int kr = n * 16 + l15;
          kfr[kf][n] = *(const short8*)(&k_lds[cur][kr * 128 +
                           ((kf * 64 + lhi * 16) ^ ((kr & 7) << 4))]);
        }

      f32x4 s[2][4];
#pragma unroll
      for (int m = 0; m < 2; ++m)
#pragma unroll
        for (int n = 0; n < 4; ++n) s[m][n] = zf;
#pragma unroll
      for (int kf = 0; kf < 2; ++kf)
#pragma unroll
        for (int n = 0; n < 4; ++n)
#pragma unroll
          for (int m = 0; m < 2; ++m)
            s[m][n] = __builtin_amdgcn_mfma_f32_16x16x32_bf16(qf[m][kf], kfr[kf][n],
                                                              s[m][n], 0, 0, 0);

      short8 vfr[2][4];
#pragma unroll
      for (int kf = 0; kf < 2; ++kf)
#pragma unroll
        for (int n = 0; n < 4; ++n) {
          int vr = n * 16 + l15;
          vfr[kf][n] = *(const short8*)(&v_lds[cur][vr * 128 +
                           ((kf * 64 + lhi * 16) ^ ((vr & 7) << 4))]);
        }

      if (t == tmask) {
#pragma unroll
        for (int m = 0; m < 2; ++m)
#pragma unroll
          for (int n = 0; n < 4; ++n)
#pragma unroll
            for (int r = 0; r < 4; ++r) {
              int kvA = kv0 + n * 16 + l15;
              int qA = qr0 + m * 16 + lhi * 4 + r;
              if (kvA > qA) s[m][n][r] = -1e30f;
            }
      }

#pragma unroll
      for (int m = 0; m < 2; ++m)
#pragma unroll
        for (int n = 0; n < 4; ++n)
#pragma unroll
          for (int r = 0; r < 4; ++r) {
            float pe = __expf(s[m][n][r] * 0.125f);
            s[m][n][r] = pe;
            lsum[m][r] += pe;
          }

#pragma unroll
      for (int m = 0; m < 2; ++m)
#pragma unroll
        for (int n = 0; n < 4; ++n)
#pragma unroll
          for (int r = 0; r < 4; ++r) {
            int row = m * 16 + lhi * 4 + r;
            *(unsigned short*)(pwl + row * 128 +
                               (((n * 16 + l15) * 2) ^ ((row & 7) << 4))) =
                f2b(s[m][n][r]);
          }
      short8 pa[2][2];
#pragma unroll
      for (int m = 0; m < 2; ++m)
#pragma unroll
        for (int kf = 0; kf < 2; ++kf) {
          int row = m * 16 + l15;
          pa[m][kf] = *(const short8*)(pwl + row * 128 +
                                       ((kf * 64 + lhi * 16) ^ ((row & 7) << 4)));
        }

#pragma unroll
      for (int kf = 0; kf < 2; ++kf)
#pragma unroll
        for (int n = 0; n < 4; ++n)
#pragma unroll
          for (int m = 0; m < 2; ++m)
            o[m][n] = __builtin_amdgcn_mfma_f32_16x16x32_bf16(pa[m][kf], vfr[kf][n],
                                                              o[m][n], 0, 0, 0);
    }

    __syncthreads();
  }

#pragma unroll
  for (int m = 0; m < 2; ++m)
#pragma unroll
    for (int r = 0; r < 4; ++r)
#pragma unroll
      for (int d = 1; d < 16; d <<= 1)
        lsum[m][r] += __shfl_xor(lsum[m][r], d, 64);

  const int b = bh >> 4, hd = bh & 15;
#pragma unroll
  for (int m = 0; m < 2; ++m)
#pragma unroll
    for (int r = 0; r < 4; ++r) {
      float inv = 1.f / lsum[m][r];
      int qrow = qr0 + m * 16 + lhi * 4 + r;
      __hip_bfloat16* orow = og + ((size_t)(b * T_ + qrow)) * C_ + hd * DH_;
#pragma unroll
      for (int n = 0; n < 4; ++n)
        orow[n * 16 + l15] = __float2bfloat16(o[m][n][r] * inv);
    }
}

// ---------------- launch ----------------
extern "C" void kernel_launch(void* const* d_in, const int* in_sizes, int n_in,
                              void* d_out, int out_size, void* d_ws, size_t ws_size,
                              hipStream_t stream) {
  const float* x      = (const float*)d_in[0];
  const float* qkv_w  = (const float*)d_in[1];
  const float* qkv_b  = (const float*)d_in[2];
  const float* proj_w = (const float*)d_in[3];
  const float* proj_b = (const float*)d_in[4];
  float* out = (float*)d_out;

  char* ws = (char*)d_ws;
  __hip_bfloat16* xb    = (__hip_bfloat16*)(ws);                 // 16 MB
  __hip_bfloat16* wqkv  = (__hip_bfloat16*)(ws + 16777216);      // 6 MB
  __hip_bfloat16* wproj = (__hip_bfloat16*)(ws + 23068672);      // 2 MB
  __hip_bfloat16* qb    = (__hip_bfloat16*)(ws + 25165824);      // 16 MB
  __hip_bfloat16* kb    = (__hip_bfloat16*)(ws + 41943040);      // 16 MB
  __hip_bfloat16* vtb   = (__hip_bfloat16*)(ws + 58720256);      // 16 MB (V^T)
  __hip_bfloat16* att   = (__hip_bfloat16*)(ws + 75497472);      // 16 MB

  cvt_all<<<2048, 256, 0, stream>>>(x, qkv_w, proj_w, xb, wqkv, wproj);

  // QKV: tile 256x192, grid 16x32 = 512 = 2 balanced rounds; bx-major decode
  gemm_bt<3><<<dim3((M_/256) * (NQKV_/192)), 1024, 0, stream>>>(
      xb, wqkv, qkv_b, 0, NQKV_/192, qb, kb, vtb, nullptr);

  attn_kernel<<<dim3(512), 512, 0, stream>>>(qb, kb, vtb, att);

  // proj: tile 256x128, grid 8x32 = 256 = exactly 1 full-chip round; bx-major
  gemm_bt<2><<<dim3((M_/256) * (C_/128)), 1024, 0, stream>>>(
      att, wproj, proj_b, 1, C_/128, nullptr, nullptr, nullptr, out);
}